// Round 1
// baseline (457.357 us; speedup 1.0000x reference)
//
#include <hip/hip_runtime.h>
#include <math.h>

#define NB   2
#define CIN  128
#define CH   64
#define NPOS 4096

// ---------------------------------------------------------------------------
// Kernel 1: q/k/v 1x1x1 conv projections. One block per (batch, 64-pos tile).
// x tile staged in LDS (128c x 64p = 32 KB); W rows read wave-uniform (s_load).
// ---------------------------------------------------------------------------
__global__ __launch_bounds__(256) void qkv_kernel(
    const float* __restrict__ x,
    const float* __restrict__ Wq, const float* __restrict__ Wk,
    const float* __restrict__ Wv,
    float* __restrict__ q, float* __restrict__ k, float* __restrict__ v)
{
    __shared__ __align__(16) float sx[CIN * 64];
    const int b  = blockIdx.y;
    const int p0 = blockIdx.x * 64;
    const int tid = threadIdx.x;

    #pragma unroll
    for (int it = 0; it < 32; ++it) {
        int idx = it * 256 + tid;
        int c = idx >> 6, pl = idx & 63;
        sx[idx] = x[(b * CIN + c) * NPOS + p0 + pl];
    }
    __syncthreads();

    const int p = tid & 63, og = tid >> 6;   // og is wave-uniform
    const float* Ws[3] = {Wq, Wk, Wv};
    float* outs[3] = {q, k, v};
    for (int mtx = 0; mtx < 3; ++mtx) {
        const float* __restrict__ W = Ws[mtx];
        float* __restrict__ o = outs[mtx];
        for (int g = 0; g < 4; ++g) {
            int o0 = og * 16 + g * 4;
            float acc[4] = {0.f, 0.f, 0.f, 0.f};
            for (int c = 0; c < CIN; ++c) {
                float xv = sx[c * 64 + p];
                #pragma unroll
                for (int r = 0; r < 4; ++r)
                    acc[r] += W[(o0 + r) * CIN + c] * xv;
            }
            #pragma unroll
            for (int r = 0; r < 4; ++r)
                o[(b * CH + o0 + r) * NPOS + p0 + p] = acc[r];
        }
    }
}

// ---------------------------------------------------------------------------
// Kernel 2: per-row softmax stats over j.  scores[i,j] = sum_c k[c,i]*q[c,j].
// Block = (batch, 32-row i tile); streams j in 64-wide tiles with online
// max/sum; stores gm[i]=rowmax, gl[i]=1/rowsum.
// Thread (ti,tj): ti=tid&15 -> i pair, tj=tid>>4 -> j quad. 2x4 reg tile.
// ---------------------------------------------------------------------------
__global__ __launch_bounds__(256) void stats_kernel(
    const float* __restrict__ k, const float* __restrict__ q,
    float* __restrict__ gm, float* __restrict__ gl)
{
    __shared__ __align__(16) float ks[CH * 32];
    __shared__ __align__(16) float qs[CH * 64];
    __shared__ float redm[32 * 16];
    __shared__ float redl[32 * 16];
    const int b  = blockIdx.y;
    const int i0 = blockIdx.x * 32;
    const int tid = threadIdx.x;

    #pragma unroll
    for (int it = 0; it < 8; ++it) {
        int idx = it * 256 + tid;
        int c = idx >> 5, il = idx & 31;
        ks[idx] = k[(b * CH + c) * NPOS + i0 + il];
    }

    const int ti = tid & 15, tj = tid >> 4;
    float macc[2] = {-INFINITY, -INFINITY};
    float lacc[2] = {0.f, 0.f};

    for (int jt = 0; jt < 64; ++jt) {
        __syncthreads();
        int j0 = jt * 64;
        #pragma unroll
        for (int it = 0; it < 16; ++it) {
            int idx = it * 256 + tid;
            int c = idx >> 6, jl = idx & 63;
            qs[idx] = q[(b * CH + c) * NPOS + j0 + jl];
        }
        __syncthreads();

        float acc[2][4] = {};
        for (int c = 0; c < CH; ++c) {
            float k0 = ks[c * 32 + ti * 2 + 0];
            float k1 = ks[c * 32 + ti * 2 + 1];
            float4 qq = *(const float4*)&qs[c * 64 + tj * 4];
            acc[0][0] += k0 * qq.x; acc[0][1] += k0 * qq.y;
            acc[0][2] += k0 * qq.z; acc[0][3] += k0 * qq.w;
            acc[1][0] += k1 * qq.x; acc[1][1] += k1 * qq.y;
            acc[1][2] += k1 * qq.z; acc[1][3] += k1 * qq.w;
        }
        #pragma unroll
        for (int r = 0; r < 2; ++r) {
            float tm = fmaxf(fmaxf(acc[r][0], acc[r][1]),
                             fmaxf(acc[r][2], acc[r][3]));
            float nm = fmaxf(macc[r], tm);
            float s = __expf(acc[r][0] - nm) + __expf(acc[r][1] - nm)
                    + __expf(acc[r][2] - nm) + __expf(acc[r][3] - nm);
            lacc[r] = lacc[r] * __expf(macc[r] - nm) + s;
            macc[r] = nm;
        }
    }

    #pragma unroll
    for (int r = 0; r < 2; ++r) {
        redm[(ti * 2 + r) * 16 + tj] = macc[r];
        redl[(ti * 2 + r) * 16 + tj] = lacc[r];
    }
    __syncthreads();
    if (tid < 32) {
        float m = -INFINITY;
        for (int t = 0; t < 16; ++t) m = fmaxf(m, redm[tid * 16 + t]);
        float l = 0.f;
        for (int t = 0; t < 16; ++t)
            l += redl[tid * 16 + t] * __expf(redm[tid * 16 + t] - m);
        gm[b * NPOS + i0 + tid] = m;
        gl[b * NPOS + i0 + tid] = 1.0f / l;
    }
}

// ---------------------------------------------------------------------------
// Kernel 3: aggregation pass.  agg[c,j] = sum_i v[c,i] * exp(s[i,j]-m_i)/l_i.
// Block = (batch, 32-col j tile); loops 64-wide i tiles:
//   matmul1: s tile (64i x 32j), thread (ti=i-quad, tj=j-pair), then weight
//   via gm/gl and store w tile to LDS; matmul2: acc2 += v^T w, thread
//   (cq=c-quad, jp=j-pair) with persistent 4x2 accumulators.
// vsT padded to 68 (16B-aligned float4 rows), ws/qs padded to 34.
// ---------------------------------------------------------------------------
__global__ __launch_bounds__(256) void agg_kernel(
    const float* __restrict__ k, const float* __restrict__ q,
    const float* __restrict__ v,
    const float* __restrict__ gm, const float* __restrict__ gl,
    float* __restrict__ agg)
{
    __shared__ __align__(16) float qs[CH * 34];
    __shared__ __align__(16) float ks[CH * 64];
    __shared__ __align__(16) float vsT[64 * 68];
    __shared__ __align__(16) float ws[64 * 34];
    const int b  = blockIdx.y;
    const int j0 = blockIdx.x * 32;
    const int tid = threadIdx.x;

    #pragma unroll
    for (int it = 0; it < 8; ++it) {
        int idx = it * 256 + tid;
        int c = idx >> 5, jl = idx & 31;
        qs[c * 34 + jl] = q[(b * CH + c) * NPOS + j0 + jl];
    }

    const int ti = tid & 15, tj = tid >> 4;  // matmul1 roles
    const int cq = tid & 15, jp = tid >> 4;  // matmul2 roles
    float acc2[4][2] = {};

    for (int it64 = 0; it64 < 64; ++it64) {
        const int i0 = it64 * 64;
        __syncthreads();
        #pragma unroll
        for (int it = 0; it < 16; ++it) {
            int idx = it * 256 + tid;
            int c = idx >> 6, il = idx & 63;
            float kv_ = k[(b * CH + c) * NPOS + i0 + il];
            float vv_ = v[(b * CH + c) * NPOS + i0 + il];
            ks[c * 64 + il] = kv_;
            vsT[il * 68 + c] = vv_;
        }
        __syncthreads();

        float acc[4][2] = {};
        for (int c = 0; c < CH; ++c) {
            float4 kk = *(const float4*)&ks[c * 64 + ti * 4];
            float2 qq = *(const float2*)&qs[c * 34 + tj * 2];
            acc[0][0] += kk.x * qq.x; acc[0][1] += kk.x * qq.y;
            acc[1][0] += kk.y * qq.x; acc[1][1] += kk.y * qq.y;
            acc[2][0] += kk.z * qq.x; acc[2][1] += kk.z * qq.y;
            acc[3][0] += kk.w * qq.x; acc[3][1] += kk.w * qq.y;
        }
        #pragma unroll
        for (int r = 0; r < 4; ++r) {
            int i = i0 + ti * 4 + r;
            float mi  = gm[b * NPOS + i];
            float rli = gl[b * NPOS + i];
            float2 w2;
            w2.x = __expf(acc[r][0] - mi) * rli;
            w2.y = __expf(acc[r][1] - mi) * rli;
            *(float2*)&ws[(ti * 4 + r) * 34 + tj * 2] = w2;
        }
        __syncthreads();

        for (int il = 0; il < 64; ++il) {
            float4 vv = *(const float4*)&vsT[il * 68 + cq * 4];
            float2 w2 = *(const float2*)&ws[il * 34 + jp * 2];
            acc2[0][0] += vv.x * w2.x; acc2[0][1] += vv.x * w2.y;
            acc2[1][0] += vv.y * w2.x; acc2[1][1] += vv.y * w2.y;
            acc2[2][0] += vv.z * w2.x; acc2[2][1] += vv.z * w2.y;
            acc2[3][0] += vv.w * w2.x; acc2[3][1] += vv.w * w2.y;
        }
    }

    #pragma unroll
    for (int r = 0; r < 4; ++r) {
        float2 o2 = make_float2(acc2[r][0], acc2[r][1]);
        *(float2*)&agg[(b * CH + cq * 4 + r) * NPOS + j0 + jp * 2] = o2;
    }
}

// ---------------------------------------------------------------------------
// Kernel 4: post projection + residual.  out[co,p] = x[co,p] + Wpost @ agg.
// ---------------------------------------------------------------------------
__global__ __launch_bounds__(256) void post_kernel(
    const float* __restrict__ x, const float* __restrict__ Wpost,
    const float* __restrict__ agg, float* __restrict__ out)
{
    __shared__ __align__(16) float sa[CH * 64];
    const int b  = blockIdx.y;
    const int p0 = blockIdx.x * 64;
    const int tid = threadIdx.x;

    #pragma unroll
    for (int it = 0; it < 16; ++it) {
        int idx = it * 256 + tid;
        int c = idx >> 6, pl = idx & 63;
        sa[idx] = agg[(b * CH + c) * NPOS + p0 + pl];
    }
    __syncthreads();

    const int p = tid & 63, og = tid >> 6;   // wave-uniform og
    for (int g = 0; g < 8; ++g) {
        int co0 = og * 32 + g * 4;
        float acc[4] = {0.f, 0.f, 0.f, 0.f};
        for (int c = 0; c < CH; ++c) {
            float a = sa[c * 64 + p];
            #pragma unroll
            for (int r = 0; r < 4; ++r)
                acc[r] += Wpost[(co0 + r) * CH + c] * a;
        }
        #pragma unroll
        for (int r = 0; r < 4; ++r) {
            int gi = (b * CIN + co0 + r) * NPOS + p0 + p;
            out[gi] = x[gi] + acc[r];
        }
    }
}

extern "C" void kernel_launch(void* const* d_in, const int* in_sizes, int n_in,
                              void* d_out, int out_size, void* d_ws, size_t ws_size,
                              hipStream_t stream) {
    const float* x     = (const float*)d_in[0];
    const float* Wq    = (const float*)d_in[1];
    const float* Wk    = (const float*)d_in[2];
    const float* Wv    = (const float*)d_in[3];
    const float* Wpost = (const float*)d_in[4];
    float* out = (float*)d_out;

    // workspace layout (floats): q,k,v,agg (NB*CH*NPOS each) + gm,gl (NB*NPOS)
    float* q   = (float*)d_ws;
    float* k   = q   + NB * CH * NPOS;
    float* v   = k   + NB * CH * NPOS;
    float* agg = v   + NB * CH * NPOS;
    float* gm  = agg + NB * CH * NPOS;
    float* gl  = gm  + NB * NPOS;

    qkv_kernel  <<<dim3(NPOS / 64, NB), 256, 0, stream>>>(x, Wq, Wk, Wv, q, k, v);
    stats_kernel<<<dim3(NPOS / 32, NB), 256, 0, stream>>>(k, q, gm, gl);
    agg_kernel  <<<dim3(NPOS / 32, NB), 256, 0, stream>>>(k, q, v, gm, gl, agg);
    post_kernel <<<dim3(NPOS / 64, NB), 256, 0, stream>>>(x, Wpost, agg, out);
}

// Round 2
// 204.756 us; speedup vs baseline: 2.2337x; 2.2337x over previous
//
#include <hip/hip_runtime.h>
#include <math.h>

#define NB   2
#define CIN  128
#define CH   64
#define NPOS 4096

typedef __attribute__((ext_vector_type(8))) short s16x8;   // 8 bf16 (4 VGPRs)
typedef __attribute__((ext_vector_type(4))) float f32x4;

__device__ __forceinline__ unsigned short f2bf(float f) {
    unsigned int u = __float_as_uint(f);
    unsigned int r = (u + 0x7FFFu + ((u >> 16) & 1u)) >> 16;
    return (unsigned short)r;
}

// ---------------------------------------------------------------------------
// Kernel 1: q/k/v projections -> bf16 in MFMA layouts.
//   kT,qT: (b, pos, c)  [A/B fragment rows, 16B contiguous per lane]
//   vb   : (b, c, pos)  [PV A-operand rows]
// Block = (b, 32-pos tile); 256 blocks total. x tile in LDS (128c x 32p).
// ---------------------------------------------------------------------------
__global__ __launch_bounds__(256) void qkv_kernel(
    const float* __restrict__ x,
    const float* __restrict__ Wq, const float* __restrict__ Wk,
    const float* __restrict__ Wv,
    unsigned short* __restrict__ kT, unsigned short* __restrict__ qT,
    unsigned short* __restrict__ vb)
{
    __shared__ __align__(16) float sx[CIN * 32];
    const int b  = blockIdx.y;
    const int p0 = blockIdx.x * 32;
    const int tid = threadIdx.x;

    #pragma unroll
    for (int it = 0; it < 16; ++it) {
        int idx = it * 256 + tid;
        int c = idx >> 5, pl = idx & 31;
        sx[idx] = x[(b * CIN + c) * NPOS + p0 + pl];
    }
    __syncthreads();

    const int p = tid & 31, og = tid >> 5;   // og in [0,8), wave-uniform halves
    const int o0 = og * 8;
    const float* Ws[3] = {Wq, Wk, Wv};
    for (int mtx = 0; mtx < 3; ++mtx) {
        const float* __restrict__ W = Ws[mtx];
        float acc[8] = {};
        for (int c = 0; c < CIN; ++c) {
            float xv = sx[c * 32 + p];
            #pragma unroll
            for (int r = 0; r < 8; ++r)
                acc[r] += W[(o0 + r) * CIN + c] * xv;
        }
        if (mtx < 2) {
            unsigned short* dst = (mtx == 0 ? qT : kT);
            unsigned short pk[8];
            #pragma unroll
            for (int r = 0; r < 8; ++r) pk[r] = f2bf(acc[r]);
            *(s16x8*)&dst[((size_t)b * NPOS + p0 + p) * CH + o0] = *(s16x8*)pk;
        } else {
            #pragma unroll
            for (int r = 0; r < 8; ++r)
                vb[((size_t)b * CH + o0 + r) * NPOS + p0 + p] = f2bf(acc[r]);
        }
    }
}

// ---------------------------------------------------------------------------
// Kernel 2: softmax denominators.  l_i = sum_j exp(s[i,j]), gl = 1/l.
// Block = (b, 16-row i-tile); 512 blocks. Each wave sweeps 1024 j's.
// A-frags (kT rows) loaded once; 2 MFMA + 4 exp per 16x16 j-tile.
// C layout (verified): col = lane&15, row = (lane>>4)*4 + reg.
// ---------------------------------------------------------------------------
__global__ __launch_bounds__(256) void stats_kernel(
    const unsigned short* __restrict__ kT,
    const unsigned short* __restrict__ qT,
    float* __restrict__ gl)
{
    __shared__ float red[4][16];
    const int b  = blockIdx.y;
    const int i0 = blockIdx.x * 16;
    const int tid = threadIdx.x;
    const int w = tid >> 6, l = tid & 63, lm = l & 15, lq = l >> 4;

    const unsigned short* kbase = kT + ((size_t)b * NPOS + i0 + lm) * CH + lq * 8;
    s16x8 a0 = *(const s16x8*)(kbase);
    s16x8 a1 = *(const s16x8*)(kbase + 32);

    float rs[4] = {0.f, 0.f, 0.f, 0.f};
    const unsigned short* qbase =
        qT + ((size_t)b * NPOS + w * 1024 + lm) * CH + lq * 8;
    for (int jt = 0; jt < 64; ++jt) {
        const unsigned short* qp = qbase + (size_t)jt * 16 * CH;
        s16x8 b0 = *(const s16x8*)(qp);
        s16x8 b1 = *(const s16x8*)(qp + 32);
        f32x4 s = {0.f, 0.f, 0.f, 0.f};
        s = __builtin_amdgcn_mfma_f32_16x16x32_bf16(a0, b0, s, 0, 0, 0);
        s = __builtin_amdgcn_mfma_f32_16x16x32_bf16(a1, b1, s, 0, 0, 0);
        rs[0] += __expf(s[0]); rs[1] += __expf(s[1]);
        rs[2] += __expf(s[2]); rs[3] += __expf(s[3]);
    }
    // reduce over the 16 column-lanes (low 4 bits of lane id)
    #pragma unroll
    for (int m = 1; m < 16; m <<= 1) {
        rs[0] += __shfl_xor(rs[0], m);
        rs[1] += __shfl_xor(rs[1], m);
        rs[2] += __shfl_xor(rs[2], m);
        rs[3] += __shfl_xor(rs[3], m);
    }
    if (lm == 0) {
        #pragma unroll
        for (int r = 0; r < 4; ++r) red[w][lq * 4 + r] = rs[r];
    }
    __syncthreads();
    if (tid < 16) {
        float lsum = red[0][tid] + red[1][tid] + red[2][tid] + red[3][tid];
        gl[b * NPOS + i0 + tid] = 1.0f / lsum;
    }
}

// ---------------------------------------------------------------------------
// Kernel 3: aggregation.  agg[c,j] = sum_i v[c,i] * exp(s[i,j]) * gl[i].
// Block = (b, 16-col j-tile); 512 blocks, 4 waves.
// Per 64-i chunk: wave w computes S for i-sub w*16 (2 MFMA), weights via
// exp*rl (rl staged in LDS, broadcast), packs bf16 to wT[j][i] (double
// buffered, stride 72 = 144B = 16B-aligned rows), then each wave does the
// PV MFMAs for its 16-c tile with persistent accumulator.
// ---------------------------------------------------------------------------
__global__ __launch_bounds__(256) void agg_kernel(
    const unsigned short* __restrict__ kT,
    const unsigned short* __restrict__ qT,
    const unsigned short* __restrict__ vb,
    const float* __restrict__ gl,
    float* __restrict__ agg)
{
    __shared__ __align__(16) float rls[NPOS];                 // 16 KB
    __shared__ __align__(16) unsigned short wT[2][16][72];    // 4.5 KB
    const int b  = blockIdx.y;
    const int j0 = blockIdx.x * 16;
    const int tid = threadIdx.x;
    const int w = tid >> 6, l = tid & 63, lm = l & 15, lq = l >> 4;

    #pragma unroll
    for (int it = 0; it < 4; ++it) {
        int idx = it * 256 + tid;
        *(float4*)&rls[idx * 4] = *(const float4*)&gl[b * NPOS + idx * 4];
    }

    const unsigned short* qbase = qT + ((size_t)b * NPOS + j0 + lm) * CH + lq * 8;
    s16x8 qb0 = *(const s16x8*)(qbase);
    s16x8 qb1 = *(const s16x8*)(qbase + 32);

    const int c0 = w * 16;
    const unsigned short* vbase = vb + ((size_t)b * CH + c0 + lm) * NPOS + lq * 8;

    f32x4 acc = {0.f, 0.f, 0.f, 0.f};
    __syncthreads();   // rls ready

    for (int ic = 0; ic < 64; ++ic) {
        const int i0 = ic * 64;
        const int isub = i0 + w * 16;
        const unsigned short* kbase =
            kT + ((size_t)b * NPOS + isub + lm) * CH + lq * 8;
        s16x8 a0 = *(const s16x8*)(kbase);
        s16x8 a1 = *(const s16x8*)(kbase + 32);
        f32x4 s = {0.f, 0.f, 0.f, 0.f};
        s = __builtin_amdgcn_mfma_f32_16x16x32_bf16(a0, qb0, s, 0, 0, 0);
        s = __builtin_amdgcn_mfma_f32_16x16x32_bf16(a1, qb1, s, 0, 0, 0);

        unsigned short pk[4];
        #pragma unroll
        for (int r = 0; r < 4; ++r) {
            float rl = rls[isub + lq * 4 + r];
            pk[r] = f2bf(__expf(s[r]) * rl);
        }
        const int buf = ic & 1;
        *(ushort4*)&wT[buf][lm][w * 16 + lq * 4] = *(ushort4*)pk;
        __syncthreads();

        const unsigned short* vp = vbase + i0;
        s16x8 va0 = *(const s16x8*)(vp);
        s16x8 va1 = *(const s16x8*)(vp + 32);
        s16x8 wb0 = *(const s16x8*)&wT[buf][lm][lq * 8];
        s16x8 wb1 = *(const s16x8*)&wT[buf][lm][32 + lq * 8];
        acc = __builtin_amdgcn_mfma_f32_16x16x32_bf16(va0, wb0, acc, 0, 0, 0);
        acc = __builtin_amdgcn_mfma_f32_16x16x32_bf16(va1, wb1, acc, 0, 0, 0);
    }

    #pragma unroll
    for (int r = 0; r < 4; ++r)
        agg[((size_t)b * CH + c0 + lq * 4 + r) * NPOS + j0 + lm] = acc[r];
}

// ---------------------------------------------------------------------------
// Kernel 4: post projection + residual (fp32).
// Block = (b, 32-pos tile); 256 blocks.
// ---------------------------------------------------------------------------
__global__ __launch_bounds__(256) void post_kernel(
    const float* __restrict__ x, const float* __restrict__ Wpost,
    const float* __restrict__ agg, float* __restrict__ out)
{
    __shared__ __align__(16) float sa[CH * 32];
    const int b  = blockIdx.y;
    const int p0 = blockIdx.x * 32;
    const int tid = threadIdx.x;

    #pragma unroll
    for (int it = 0; it < 8; ++it) {
        int idx = it * 256 + tid;
        int c = idx >> 5, pl = idx & 31;
        sa[idx] = agg[((size_t)b * CH + c) * NPOS + p0 + pl];
    }
    __syncthreads();

    const int p = tid & 31, og = tid >> 5;
    const int o0 = og * 16;
    float acc[16] = {};
    for (int c = 0; c < CH; ++c) {
        float a = sa[c * 32 + p];
        #pragma unroll
        for (int r = 0; r < 16; ++r)
            acc[r] += Wpost[(o0 + r) * CH + c] * a;
    }
    #pragma unroll
    for (int r = 0; r < 16; ++r) {
        size_t gi = ((size_t)b * CIN + o0 + r) * NPOS + p0 + p;
        out[gi] = x[gi] + acc[r];
    }
}

extern "C" void kernel_launch(void* const* d_in, const int* in_sizes, int n_in,
                              void* d_out, int out_size, void* d_ws, size_t ws_size,
                              hipStream_t stream) {
    const float* x     = (const float*)d_in[0];
    const float* Wq    = (const float*)d_in[1];
    const float* Wk    = (const float*)d_in[2];
    const float* Wv    = (const float*)d_in[3];
    const float* Wpost = (const float*)d_in[4];
    float* out = (float*)d_out;

    // workspace: agg fp32, gl fp32, then bf16 kT,qT,vb (all 16B-aligned)
    float* agg = (float*)d_ws;
    float* gl  = agg + (size_t)NB * CH * NPOS;
    unsigned short* kT = (unsigned short*)(gl + (size_t)NB * NPOS);
    unsigned short* qT = kT + (size_t)NB * NPOS * CH;
    unsigned short* vb = qT + (size_t)NB * NPOS * CH;

    qkv_kernel  <<<dim3(NPOS / 32, NB), 256, 0, stream>>>(x, Wq, Wk, Wv, kT, qT, vb);
    stats_kernel<<<dim3(NPOS / 16, NB), 256, 0, stream>>>(kT, qT, gl);
    agg_kernel  <<<dim3(NPOS / 16, NB), 256, 0, stream>>>(kT, qT, vb, gl, agg);
    post_kernel <<<dim3(NPOS / 32, NB), 256, 0, stream>>>(x, Wpost, agg, out);
}

// Round 3
// 167.856 us; speedup vs baseline: 2.7247x; 1.2198x over previous
//
#include <hip/hip_runtime.h>
#include <math.h>

#define NB   2
#define CIN  128
#define CH   64
#define NPOS 4096

typedef __attribute__((ext_vector_type(8))) short s16x8;   // 8 bf16 (4 VGPRs)
typedef __attribute__((ext_vector_type(4))) float f32x4;

// fp32 -> bf16 bits, round-to-nearest-even
__device__ __forceinline__ unsigned int bfrne(float f) {
    unsigned int u = __float_as_uint(f);
    return (u + 0x7FFFu + ((u >> 16) & 1u)) >> 16;
}
// pack two fp32 -> bf16x2 dword (RNE); element0 = low16
__device__ __forceinline__ unsigned int pk_rne(float lo, float hi) {
    return bfrne(lo) | (bfrne(hi) << 16);
}
// fast half-up rounding pack, for non-negative values (exp outputs)
__device__ __forceinline__ unsigned int pk_fast(float lo, float hi) {
    unsigned int a = (__float_as_uint(lo) + 0x8000u) >> 16;
    unsigned int b = (__float_as_uint(hi) + 0x8000u) & 0xFFFF0000u;
    return a | b;
}

// ---------------------------------------------------------------------------
// Kernel 1: q/k/v projections via MFMA.  A = W (bf16-rounded), B = x split
// into hi+lo bf16 (restores fp32-x accuracy; only W rounding remains).
//   kT,qT: (b,pos,c) bf16;  v32: (b,c,pos) fp32 (consumed by stats).
// Block = (b, 32-pos); wave: psub=(w&1)*16, tile-half=w>>1 (6 of 12 o-tiles).
// ---------------------------------------------------------------------------
__global__ __launch_bounds__(256) void qkv_kernel(
    const float* __restrict__ x,
    const float* __restrict__ Wq, const float* __restrict__ Wk,
    const float* __restrict__ Wv,
    unsigned short* __restrict__ kT, unsigned short* __restrict__ qT,
    float* __restrict__ v32)
{
    const int b  = blockIdx.y;
    const int p0 = blockIdx.x * 32;
    const int tid = threadIdx.x;
    const int w = tid >> 6, l = tid & 63, lm = l & 15, lq = l >> 4;
    const int psub = (w & 1) * 16, thalf = w >> 1;
    const int p = p0 + psub + lm;

    // B-frags: x[c][p], k=c in 4 chunks of 32; hi/lo split
    s16x8 Bhi[4], Blo[4];
    #pragma unroll
    for (int ck = 0; ck < 4; ++ck) {
        const float* xp = x + ((size_t)b * CIN + ck * 32 + lq * 8) * NPOS + p;
        float xv[8];
        #pragma unroll
        for (int j = 0; j < 8; ++j) xv[j] = xp[(size_t)j * NPOS];
        union { unsigned int u[4]; s16x8 v; } chv, clv;
        #pragma unroll
        for (int j = 0; j < 4; ++j) {
            unsigned int h0 = bfrne(xv[2*j]), h1 = bfrne(xv[2*j+1]);
            float f0 = __uint_as_float(h0 << 16);
            float f1 = __uint_as_float(h1 << 16);
            chv.u[j] = h0 | (h1 << 16);
            clv.u[j] = pk_rne(xv[2*j] - f0, xv[2*j+1] - f1);
        }
        Bhi[ck] = chv.v; Blo[ck] = clv.v;
    }

    for (int t6 = 0; t6 < 6; ++t6) {
        const int tile = thalf * 6 + t6;
        const int mat = tile >> 2, o0 = (tile & 3) * 16;
        const float* __restrict__ W = (mat == 0) ? Wq : (mat == 1) ? Wk : Wv;
        f32x4 acc = {0.f, 0.f, 0.f, 0.f};
        #pragma unroll
        for (int ck = 0; ck < 4; ++ck) {
            const float* wp = W + (o0 + lm) * CIN + ck * 32 + lq * 8;
            union { unsigned int u[4]; s16x8 v; } ca;
            #pragma unroll
            for (int j = 0; j < 4; ++j) ca.u[j] = pk_rne(wp[2*j], wp[2*j+1]);
            acc = __builtin_amdgcn_mfma_f32_16x16x32_bf16(ca.v, Bhi[ck], acc, 0,0,0);
            acc = __builtin_amdgcn_mfma_f32_16x16x32_bf16(ca.v, Blo[ck], acc, 0,0,0);
        }
        // C layout: col=lane&15 (=p), row=4*lq+r (=o_local)
        if (mat < 2) {
            unsigned short* dst = (mat == 0) ? qT : kT;
            uint2 st = make_uint2(pk_rne(acc[0], acc[1]), pk_rne(acc[2], acc[3]));
            *(uint2*)&dst[((size_t)b * NPOS + p) * CH + o0 + lq * 4] = st;
        } else {
            #pragma unroll
            for (int r = 0; r < 4; ++r)
                v32[((size_t)b * CH + o0 + lq * 4 + r) * NPOS + p] = acc[r];
        }
    }
}

// ---------------------------------------------------------------------------
// Kernel 2: softmax denominators l_i = sum_j exp(s[i,j]) (no-max: |s|<~50,
// fp32 exp safe), then emits v' = v * (1/l) as bf16 (b,c,pos).
// Block = (b, 16-i); waves sweep disjoint 1024-j ranges, prefetched.
// ---------------------------------------------------------------------------
__global__ __launch_bounds__(256) void stats_kernel(
    const unsigned short* __restrict__ kT,
    const unsigned short* __restrict__ qT,
    const float* __restrict__ v32,
    unsigned short* __restrict__ vbs)
{
    __shared__ float red[4][16];
    __shared__ float gls[16];
    const int b  = blockIdx.y;
    const int i0 = blockIdx.x * 16;
    const int tid = threadIdx.x;
    const int w = tid >> 6, l = tid & 63, lm = l & 15, lq = l >> 4;

    const unsigned short* kb = kT + ((size_t)b * NPOS + i0 + lm) * CH + lq * 8;
    s16x8 a0 = *(const s16x8*)kb;
    s16x8 a1 = *(const s16x8*)(kb + 32);

    const unsigned short* qb = qT + ((size_t)b * NPOS + w * 1024 + lm) * CH + lq * 8;
    s16x8 nb0 = *(const s16x8*)qb;
    s16x8 nb1 = *(const s16x8*)(qb + 32);
    float rs0 = 0.f, rs1 = 0.f, rs2 = 0.f, rs3 = 0.f;
    for (int jt = 0; jt < 64; ++jt) {
        s16x8 b0 = nb0, b1 = nb1;
        const unsigned short* qn = (jt < 63) ? qb + (size_t)(jt + 1) * 16 * CH : qb;
        nb0 = *(const s16x8*)qn;
        nb1 = *(const s16x8*)(qn + 32);
        f32x4 s = {0.f, 0.f, 0.f, 0.f};
        s = __builtin_amdgcn_mfma_f32_16x16x32_bf16(a0, b0, s, 0, 0, 0);
        s = __builtin_amdgcn_mfma_f32_16x16x32_bf16(a1, b1, s, 0, 0, 0);
        rs0 += __expf(s[0]); rs1 += __expf(s[1]);
        rs2 += __expf(s[2]); rs3 += __expf(s[3]);
    }
    #pragma unroll
    for (int m = 1; m < 16; m <<= 1) {
        rs0 += __shfl_xor(rs0, m); rs1 += __shfl_xor(rs1, m);
        rs2 += __shfl_xor(rs2, m); rs3 += __shfl_xor(rs3, m);
    }
    if (lm == 0) {
        red[w][lq * 4 + 0] = rs0; red[w][lq * 4 + 1] = rs1;
        red[w][lq * 4 + 2] = rs2; red[w][lq * 4 + 3] = rs3;
    }
    __syncthreads();
    if (tid < 16)
        gls[tid] = 1.0f / (red[0][tid] + red[1][tid] + red[2][tid] + red[3][tid]);
    __syncthreads();

    // v' = v32 * gl, bf16, (c,pos): thread t -> c=t>>2, 4 i's
    {
        const int c = tid >> 2, qq = tid & 3;
        size_t base = ((size_t)b * CH + c) * NPOS + i0 + qq * 4;
        float4 vv = *(const float4*)&v32[base];
        uint2 st = make_uint2(
            pk_rne(vv.x * gls[qq*4+0], vv.y * gls[qq*4+1]),
            pk_rne(vv.z * gls[qq*4+2], vv.w * gls[qq*4+3]));
        *(uint2*)&vbs[base] = st;
    }
}

// ---------------------------------------------------------------------------
// Kernel 3: aggregation, barrier-free waves.  U[half][c][j] partial sums.
// Block = (32-j, i-half, b); wave: jsub=(w&1)*16, i-interleave wi=w>>1.
// Per 32-i chunk: 4 score MFMAs -> exp -> pack -> 8 bpermutes (C->B
// transpose in-register) -> 4 PV MFMAs (64c).  Register-double-buffered
// k/v' fragment prefetch; single barrier at the end for the pair-reduce.
// ---------------------------------------------------------------------------
__global__ __launch_bounds__(256) void agg_kernel(
    const unsigned short* __restrict__ kT,
    const unsigned short* __restrict__ qT,
    const unsigned short* __restrict__ vbs,
    float* __restrict__ U)
{
    __shared__ float red[2][4][64][4];   // 8 KB
    const int b    = blockIdx.z;
    const int half = blockIdx.y;
    const int j0   = blockIdx.x * 32;
    const int tid = threadIdx.x;
    const int w = tid >> 6, l = tid & 63, lm = l & 15, lq = l >> 4;
    const int jsub = (w & 1) * 16, wi = w >> 1;

    const unsigned short* qb =
        qT + ((size_t)b * NPOS + j0 + jsub + lm) * CH + lq * 8;
    s16x8 qb0 = *(const s16x8*)qb;
    s16x8 qb1 = *(const s16x8*)(qb + 32);

    // bpermute byte-addresses (loop-invariant):
    // dest dword d wants i-pair (8*lq+2d) -> src lane = lm + 16*(2*(lq&1)+(d>>1))
    int addr[4];
    #pragma unroll
    for (int d = 0; d < 4; ++d)
        addr[d] = (lm + 16 * (2 * (lq & 1) + (d >> 1))) << 2;
    const bool lowhalf = (lq < 2);   // i<16 sources from S0 pack, else S1

    const size_t kTbase = (size_t)b * NPOS * CH;
    const size_t vbase  = (size_t)b * CH * NPOS;

    f32x4 acc0 = {0,0,0,0}, acc1 = {0,0,0,0}, acc2 = {0,0,0,0}, acc3 = {0,0,0,0};

    int i0c = half * 2048 + wi * 32;   // chunk t: half*2048 + (2t+wi)*32
    const unsigned short* kp = kT + kTbase + (size_t)(i0c + lm) * CH + lq * 8;
    s16x8 nk00 = *(const s16x8*)kp;
    s16x8 nk01 = *(const s16x8*)(kp + 32);
    s16x8 nk10 = *(const s16x8*)(kp + 16 * CH);
    s16x8 nk11 = *(const s16x8*)(kp + 16 * CH + 32);
    const unsigned short* vp = vbs + vbase + (size_t)lm * NPOS + i0c + lq * 8;
    s16x8 nv0 = *(const s16x8*)(vp);
    s16x8 nv1 = *(const s16x8*)(vp + 16 * NPOS);
    s16x8 nv2 = *(const s16x8*)(vp + 32 * NPOS);
    s16x8 nv3 = *(const s16x8*)(vp + 48 * NPOS);

    for (int t = 0; t < 32; ++t) {
        s16x8 k00 = nk00, k01 = nk01, k10 = nk10, k11 = nk11;
        s16x8 v0 = nv0, v1 = nv1, v2 = nv2, v3 = nv3;
        const int tn = (t < 31) ? t + 1 : 0;
        i0c = half * 2048 + (2 * tn + wi) * 32;
        const unsigned short* kpn =
            kT + kTbase + (size_t)(i0c + lm) * CH + lq * 8;
        nk00 = *(const s16x8*)kpn;
        nk01 = *(const s16x8*)(kpn + 32);
        nk10 = *(const s16x8*)(kpn + 16 * CH);
        nk11 = *(const s16x8*)(kpn + 16 * CH + 32);
        const unsigned short* vpn =
            vbs + vbase + (size_t)lm * NPOS + i0c + lq * 8;
        nv0 = *(const s16x8*)(vpn);
        nv1 = *(const s16x8*)(vpn + 16 * NPOS);
        nv2 = *(const s16x8*)(vpn + 32 * NPOS);
        nv3 = *(const s16x8*)(vpn + 48 * NPOS);

        f32x4 s0 = {0,0,0,0}, s1 = {0,0,0,0};
        s0 = __builtin_amdgcn_mfma_f32_16x16x32_bf16(k00, qb0, s0, 0,0,0);
        s0 = __builtin_amdgcn_mfma_f32_16x16x32_bf16(k01, qb1, s0, 0,0,0);
        s1 = __builtin_amdgcn_mfma_f32_16x16x32_bf16(k10, qb0, s1, 0,0,0);
        s1 = __builtin_amdgcn_mfma_f32_16x16x32_bf16(k11, qb1, s1, 0,0,0);

        // w = exp(s) packed as bf16 pairs: P[p] = (w[4*lq+2p], w[4*lq+2p+1])
        unsigned int P0[2], P1[2];
        P0[0] = pk_fast(__expf(s0[0]), __expf(s0[1]));
        P0[1] = pk_fast(__expf(s0[2]), __expf(s0[3]));
        P1[0] = pk_fast(__expf(s1[0]), __expf(s1[1]));
        P1[1] = pk_fast(__expf(s1[2]), __expf(s1[3]));

        // transpose C->B via bpermute
        union { unsigned int u[4]; s16x8 v; } B;
        #pragma unroll
        for (int d = 0; d < 4; ++d) {
            int t0 = __builtin_amdgcn_ds_bpermute(addr[d], (int)P0[d & 1]);
            int t1 = __builtin_amdgcn_ds_bpermute(addr[d], (int)P1[d & 1]);
            B.u[d] = lowhalf ? (unsigned int)t0 : (unsigned int)t1;
        }

        acc0 = __builtin_amdgcn_mfma_f32_16x16x32_bf16(v0, B.v, acc0, 0,0,0);
        acc1 = __builtin_amdgcn_mfma_f32_16x16x32_bf16(v1, B.v, acc1, 0,0,0);
        acc2 = __builtin_amdgcn_mfma_f32_16x16x32_bf16(v2, B.v, acc2, 0,0,0);
        acc3 = __builtin_amdgcn_mfma_f32_16x16x32_bf16(v3, B.v, acc3, 0,0,0);
    }

    // pair-reduce (waves 0+2 share jsub=0, 1+3 share jsub=16), write U
    if (w >= 2) {
        *(f32x4*)&red[w - 2][0][l][0] = acc0;
        *(f32x4*)&red[w - 2][1][l][0] = acc1;
        *(f32x4*)&red[w - 2][2][l][0] = acc2;
        *(f32x4*)&red[w - 2][3][l][0] = acc3;
    }
    __syncthreads();
    if (w < 2) {
        float* Up = U + (size_t)half * NB * NPOS * CH
                  + ((size_t)b * NPOS + j0 + jsub + lm) * CH;
        f32x4 a[4] = {acc0, acc1, acc2, acc3};
        #pragma unroll
        for (int ct = 0; ct < 4; ++ct) {
            f32x4 o = a[ct] + *(const f32x4*)&red[w][ct][l][0];
            *(f32x4*)&Up[ct * 16 + lq * 4] = o;
        }
    }
}

// ---------------------------------------------------------------------------
// Kernel 4: post projection + residual via MFMA.  B = (U0+U1) bf16, A = Wpost
// bf16, epilogue adds x in fp32.  Block = (b, 32-pos).
// ---------------------------------------------------------------------------
__global__ __launch_bounds__(256) void post_kernel(
    const float* __restrict__ x, const float* __restrict__ Wpost,
    const float* __restrict__ U, float* __restrict__ out)
{
    const int b  = blockIdx.y;
    const int p0 = blockIdx.x * 32;
    const int tid = threadIdx.x;
    const int w = tid >> 6, l = tid & 63, lm = l & 15, lq = l >> 4;
    const int psub = (w & 1) * 16, ohalf = w >> 1;
    const int p = p0 + psub + lm;

    s16x8 Bf[2];
    const float* u0 = U + ((size_t)b * NPOS + p) * CH;
    const float* u1 = u0 + (size_t)NB * NPOS * CH;
    #pragma unroll
    for (int ck = 0; ck < 2; ++ck) {
        const float* a0 = u0 + ck * 32 + lq * 8;
        const float* a1 = u1 + ck * 32 + lq * 8;
        float sv[8];
        #pragma unroll
        for (int j = 0; j < 8; ++j) sv[j] = a0[j] + a1[j];
        union { unsigned int u[4]; s16x8 v; } cb;
        #pragma unroll
        for (int j = 0; j < 4; ++j) cb.u[j] = pk_rne(sv[2*j], sv[2*j+1]);
        Bf[ck] = cb.v;
    }

    #pragma unroll
    for (int ot = 0; ot < 4; ++ot) {
        const int o0 = (ohalf * 4 + ot) * 16;
        f32x4 acc = {0.f, 0.f, 0.f, 0.f};
        #pragma unroll
        for (int ck = 0; ck < 2; ++ck) {
            const float* wp = Wpost + (o0 + lm) * CH + ck * 32 + lq * 8;
            union { unsigned int u[4]; s16x8 v; } ca;
            #pragma unroll
            for (int j = 0; j < 4; ++j) ca.u[j] = pk_rne(wp[2*j], wp[2*j+1]);
            acc = __builtin_amdgcn_mfma_f32_16x16x32_bf16(ca.v, Bf[ck], acc, 0,0,0);
        }
        #pragma unroll
        for (int r = 0; r < 4; ++r) {
            size_t gi = ((size_t)b * CIN + o0 + lq * 4 + r) * NPOS + p;
            out[gi] = x[gi] + acc[r];
        }
    }
}

extern "C" void kernel_launch(void* const* d_in, const int* in_sizes, int n_in,
                              void* d_out, int out_size, void* d_ws, size_t ws_size,
                              hipStream_t stream) {
    const float* x     = (const float*)d_in[0];
    const float* Wq    = (const float*)d_in[1];
    const float* Wk    = (const float*)d_in[2];
    const float* Wv    = (const float*)d_in[3];
    const float* Wpost = (const float*)d_in[4];
    float* out = (float*)d_out;

    // ws layout: kT(1MB) qT(1MB) vbs(1MB) U(4MB; first 2MB doubles as v32)
    unsigned short* kT  = (unsigned short*)d_ws;
    unsigned short* qT  = kT + (size_t)NB * NPOS * CH;
    unsigned short* vbs = qT + (size_t)NB * NPOS * CH;
    float* U   = (float*)(vbs + (size_t)NB * NPOS * CH);
    float* v32 = U;   // consumed by stats before agg writes U

    qkv_kernel  <<<dim3(NPOS / 32, NB),    256, 0, stream>>>(x, Wq, Wk, Wv, kT, qT, v32);
    stats_kernel<<<dim3(NPOS / 16, NB),    256, 0, stream>>>(kT, qT, v32, vbs);
    agg_kernel  <<<dim3(NPOS / 32, 2, NB), 256, 0, stream>>>(kT, qT, vbs, U);
    post_kernel <<<dim3(NPOS / 32, NB),    256, 0, stream>>>(x, Wpost, U, out);
}

// Round 4
// 126.059 us; speedup vs baseline: 3.6281x; 1.3316x over previous
//
#include <hip/hip_runtime.h>
#include <math.h>

#define NB   2
#define CIN  128
#define CH   64
#define NPOS 4096

typedef __attribute__((ext_vector_type(8))) short s16x8;   // 8 bf16 (4 VGPRs)
typedef __attribute__((ext_vector_type(4))) float f32x4;

// fp32 -> bf16 bits, round-to-nearest-even
__device__ __forceinline__ unsigned int bfrne(float f) {
    unsigned int u = __float_as_uint(f);
    return (u + 0x7FFFu + ((u >> 16) & 1u)) >> 16;
}
__device__ __forceinline__ unsigned int pk_rne(float lo, float hi) {
    return bfrne(lo) | (bfrne(hi) << 16);
}
// fast half-up pack for non-negative values (exp outputs)
__device__ __forceinline__ unsigned int pk_fast(float lo, float hi) {
    unsigned int a = (__float_as_uint(lo) + 0x8000u) >> 16;
    unsigned int b = (__float_as_uint(hi) + 0x8000u) & 0xFFFF0000u;
    return a | b;
}

// ---------------------------------------------------------------------------
// Kernel 1: q/k/v projections via MFMA.  x staged+transposed in LDS (xT[p][c],
// stride 132 -> 2-way-free banks, 16B-aligned rows) so B-frag builds are
// ds_read_b128 not NPOS-stride gathers.  A = W bf16 (global, L2-hot),
// B = x split hi+lo bf16 (keeps fp32-x accuracy).
//   kT,qT: (b,pos,c) bf16;  v32: (b,c,pos) fp32.
// ---------------------------------------------------------------------------
#define XTS 132
__global__ __launch_bounds__(256) void qkv_kernel(
    const float* __restrict__ x,
    const float* __restrict__ Wq, const float* __restrict__ Wk,
    const float* __restrict__ Wv,
    unsigned short* __restrict__ kT, unsigned short* __restrict__ qT,
    float* __restrict__ v32)
{
    __shared__ __align__(16) float xT[32 * XTS];   // 16.9 KB
    const int b  = blockIdx.y;
    const int p0 = blockIdx.x * 32;
    const int tid = threadIdx.x;

    #pragma unroll
    for (int it = 0; it < 4; ++it) {
        int idx = it * 256 + tid;                  // 0..1023
        int c = idx >> 3, p4 = (idx & 7) * 4;
        float4 g = *(const float4*)&x[((size_t)b * CIN + c) * NPOS + p0 + p4];
        xT[(p4 + 0) * XTS + c] = g.x;
        xT[(p4 + 1) * XTS + c] = g.y;
        xT[(p4 + 2) * XTS + c] = g.z;
        xT[(p4 + 3) * XTS + c] = g.w;
    }
    __syncthreads();

    const int w = tid >> 6, l = tid & 63, lm = l & 15, lq = l >> 4;
    const int psub = (w & 1) * 16, thalf = w >> 1;
    const int p = p0 + psub + lm;

    s16x8 Bhi[4], Blo[4];
    #pragma unroll
    for (int ck = 0; ck < 4; ++ck) {
        const float* xr = &xT[(psub + lm) * XTS + ck * 32 + lq * 8];
        union { unsigned int u[4]; s16x8 v; } chv, clv;
        #pragma unroll
        for (int j = 0; j < 4; ++j) {
            float x0 = xr[2 * j], x1 = xr[2 * j + 1];
            unsigned int h0 = bfrne(x0), h1 = bfrne(x1);
            chv.u[j] = h0 | (h1 << 16);
            clv.u[j] = pk_rne(x0 - __uint_as_float(h0 << 16),
                              x1 - __uint_as_float(h1 << 16));
        }
        Bhi[ck] = chv.v; Blo[ck] = clv.v;
    }

    for (int t6 = 0; t6 < 6; ++t6) {
        const int tile = thalf * 6 + t6;
        const int mat = tile >> 2, o0 = (tile & 3) * 16;
        const float* __restrict__ W = (mat == 0) ? Wq : (mat == 1) ? Wk : Wv;
        f32x4 acc = {0.f, 0.f, 0.f, 0.f};
        #pragma unroll
        for (int ck = 0; ck < 4; ++ck) {
            const float* wp = W + (o0 + lm) * CIN + ck * 32 + lq * 8;
            union { unsigned int u[4]; s16x8 v; } ca;
            #pragma unroll
            for (int j = 0; j < 4; ++j) ca.u[j] = pk_rne(wp[2*j], wp[2*j+1]);
            acc = __builtin_amdgcn_mfma_f32_16x16x32_bf16(ca.v, Bhi[ck], acc, 0,0,0);
            acc = __builtin_amdgcn_mfma_f32_16x16x32_bf16(ca.v, Blo[ck], acc, 0,0,0);
        }
        if (mat < 2) {
            unsigned short* dst = (mat == 0) ? qT : kT;
            uint2 st = make_uint2(pk_rne(acc[0], acc[1]), pk_rne(acc[2], acc[3]));
            *(uint2*)&dst[((size_t)b * NPOS + p) * CH + o0 + lq * 4] = st;
        } else {
            #pragma unroll
            for (int r = 0; r < 4; ++r)
                v32[((size_t)b * CH + o0 + lq * 4 + r) * NPOS + p] = acc[r];
        }
    }
}

// ---------------------------------------------------------------------------
// Kernel 2: softmax denominator partials.  lpart[jq][b][i] = sum over the
// jq-th quarter of j of exp(s[i,j]).  Block = (128-i tile, jq, b) = 256
// blocks.  Wave w owns 32 i (A-frags reg-resident); q staged per 64-j tile
// in frag-ordered LDS blocks (1 KB, lane l at l*16B -> conflict-free).
// ---------------------------------------------------------------------------
__global__ __launch_bounds__(256) void stats_kernel(
    const unsigned short* __restrict__ kT,
    const unsigned short* __restrict__ qT,
    float* __restrict__ lpart)
{
    __shared__ __align__(16) unsigned short qbuf[4096];   // 8 KB
    const int b  = blockIdx.z;
    const int jq = blockIdx.y;
    const int i0 = blockIdx.x * 128;
    const int tid = threadIdx.x;
    const int w = tid >> 6, l = tid & 63, lm = l & 15, lq = l >> 4;

    s16x8 a[2][2];
    #pragma unroll
    for (int s = 0; s < 2; ++s)
        #pragma unroll
        for (int kc = 0; kc < 2; ++kc)
            a[s][kc] = *(const s16x8*)&kT[
                ((size_t)b * NPOS + i0 + w * 32 + s * 16 + lm) * CH + kc * 32 + lq * 8];

    // wave w stages frag-blocks {2w, 2w+1}: j-subtile w, kc = 0/1
    const unsigned short* qpt =
        qT + ((size_t)b * NPOS + jq * 1024 + w * 16 + lm) * CH + lq * 8;
    s16x8 st0 = *(const s16x8*)(qpt);
    s16x8 st1 = *(const s16x8*)(qpt + 32);

    float rs[2][4] = {};
    for (int t = 0; t < 16; ++t) {
        *(s16x8*)&qbuf[(2 * w + 0) * 512 + l * 8] = st0;
        *(s16x8*)&qbuf[(2 * w + 1) * 512 + l * 8] = st1;
        __syncthreads();
        if (t < 15) {
            const unsigned short* qn = qpt + (size_t)(t + 1) * 64 * CH;
            st0 = *(const s16x8*)(qn);
            st1 = *(const s16x8*)(qn + 32);
        }
        #pragma unroll
        for (int js = 0; js < 4; ++js) {
            s16x8 b0 = *(const s16x8*)&qbuf[(js * 2 + 0) * 512 + l * 8];
            s16x8 b1 = *(const s16x8*)&qbuf[(js * 2 + 1) * 512 + l * 8];
            #pragma unroll
            for (int s = 0; s < 2; ++s) {
                f32x4 sc = {0.f, 0.f, 0.f, 0.f};
                sc = __builtin_amdgcn_mfma_f32_16x16x32_bf16(a[s][0], b0, sc, 0,0,0);
                sc = __builtin_amdgcn_mfma_f32_16x16x32_bf16(a[s][1], b1, sc, 0,0,0);
                rs[s][0] += __expf(sc[0]); rs[s][1] += __expf(sc[1]);
                rs[s][2] += __expf(sc[2]); rs[s][3] += __expf(sc[3]);
            }
        }
        __syncthreads();
    }

    // reduce over the 16 column-lanes (j), then store partials
    #pragma unroll
    for (int s = 0; s < 2; ++s)
        #pragma unroll
        for (int r = 0; r < 4; ++r) {
            #pragma unroll
            for (int m = 1; m < 16; m <<= 1)
                rs[s][r] += __shfl_xor(rs[s][r], m);
        }
    if (lm == 0) {
        #pragma unroll
        for (int s = 0; s < 2; ++s)
            #pragma unroll
            for (int r = 0; r < 4; ++r)
                lpart[(size_t)jq * NB * NPOS + b * NPOS
                      + i0 + w * 32 + s * 16 + lq * 4 + r] = rs[s][r];
    }
}

// ---------------------------------------------------------------------------
// Kernel 3: combine partial denominators and prescale v:
//   vbs[c,i] = bf16( v32[c,i] / (sum_q lpart[q][i]) )
// ---------------------------------------------------------------------------
__global__ __launch_bounds__(256) void combine_kernel(
    const float* __restrict__ lpart, const float* __restrict__ v32,
    unsigned short* __restrict__ vbs)
{
    const int idx4 = blockIdx.x * 256 + threadIdx.x;
    const int base = idx4 * 4;                 // flat (b,c,i)
    const int b = base >> 18;
    const int i = base & (NPOS - 1);
    const float* lp = lpart + b * NPOS + i;
    float4 l0 = *(const float4*)(lp);
    float4 l1 = *(const float4*)(lp + 1 * NB * NPOS);
    float4 l2 = *(const float4*)(lp + 2 * NB * NPOS);
    float4 l3 = *(const float4*)(lp + 3 * NB * NPOS);
    float sx = l0.x + l1.x + l2.x + l3.x;
    float sy = l0.y + l1.y + l2.y + l3.y;
    float sz = l0.z + l1.z + l2.z + l3.z;
    float sw = l0.w + l1.w + l2.w + l3.w;
    float4 v = *(const float4*)&v32[base];
    uint2 st = make_uint2(pk_rne(v.x / sx, v.y / sy),
                          pk_rne(v.z / sz, v.w / sw));
    *(uint2*)&vbs[base] = st;
}

// ---------------------------------------------------------------------------
// Kernel 4: aggregation.  U[iq][b][j][c] = sum over i-quarter of
// v'[c,i]*exp(s[i,j]).  Block = (128-j tile, iq, b) = 256 blocks, 4 waves.
// Wave w owns j-slice w*32 (q-frags reg-resident, 64c x 32j accumulator).
// Per 32-i iter: k-tile + v-tile staged in frag-ordered LDS (each wave one
// 1 KB block each, reg-prefetched); 8 score MFMAs -> exp -> bpermute C->B
// transpose (in-register, verified) -> 8 PV MFMAs.  2 barriers/iter.
// ---------------------------------------------------------------------------
__global__ __launch_bounds__(256) void agg_kernel(
    const unsigned short* __restrict__ kT,
    const unsigned short* __restrict__ qT,
    const unsigned short* __restrict__ vbs,
    float* __restrict__ U)
{
    __shared__ __align__(16) unsigned short kbuf[2048];   // 4 KB
    __shared__ __align__(16) unsigned short vbuf[2048];   // 4 KB
    const int b  = blockIdx.z;
    const int iq = blockIdx.y;
    const int j0 = blockIdx.x * 128;
    const int tid = threadIdx.x;
    const int w = tid >> 6, l = tid & 63, lm = l & 15, lq = l >> 4;

    s16x8 qb[2][2];
    #pragma unroll
    for (int js = 0; js < 2; ++js)
        #pragma unroll
        for (int kc = 0; kc < 2; ++kc)
            qb[js][kc] = *(const s16x8*)&qT[
                ((size_t)b * NPOS + j0 + w * 32 + js * 16 + lm) * CH + kc * 32 + lq * 8];

    int addr[4];
    #pragma unroll
    for (int d = 0; d < 4; ++d)
        addr[d] = (lm + 16 * (2 * (lq & 1) + (d >> 1))) << 2;
    const bool lowhalf = (lq < 2);

    // staging pointers: wave w stages k frag-block w (s=w>>1, kc=w&1) and
    // v frag-block w (c-subtile w)
    const unsigned short* kpt = kT
        + ((size_t)b * NPOS + iq * 1024 + (w >> 1) * 16 + lm) * CH
        + (w & 1) * 32 + lq * 8;
    const unsigned short* vpt = vbs
        + ((size_t)b * CH + w * 16 + lm) * NPOS + iq * 1024 + lq * 8;

    f32x4 acc[2][4] = {};
    s16x8 kst = *(const s16x8*)kpt;
    s16x8 vst = *(const s16x8*)vpt;

    for (int t = 0; t < 32; ++t) {
        *(s16x8*)&kbuf[w * 512 + l * 8] = kst;
        *(s16x8*)&vbuf[w * 512 + l * 8] = vst;
        __syncthreads();
        if (t < 31) {
            kst = *(const s16x8*)(kpt + (t + 1) * 32 * CH);
            vst = *(const s16x8*)(vpt + (t + 1) * 32);
        }
        s16x8 kA[2][2], vA[4];
        #pragma unroll
        for (int s = 0; s < 2; ++s)
            #pragma unroll
            for (int kc = 0; kc < 2; ++kc)
                kA[s][kc] = *(const s16x8*)&kbuf[(s * 2 + kc) * 512 + l * 8];
        #pragma unroll
        for (int cs = 0; cs < 4; ++cs)
            vA[cs] = *(const s16x8*)&vbuf[cs * 512 + l * 8];

        #pragma unroll
        for (int js = 0; js < 2; ++js) {
            f32x4 s0 = {0,0,0,0}, s1 = {0,0,0,0};
            s0 = __builtin_amdgcn_mfma_f32_16x16x32_bf16(kA[0][0], qb[js][0], s0, 0,0,0);
            s0 = __builtin_amdgcn_mfma_f32_16x16x32_bf16(kA[0][1], qb[js][1], s0, 0,0,0);
            s1 = __builtin_amdgcn_mfma_f32_16x16x32_bf16(kA[1][0], qb[js][0], s1, 0,0,0);
            s1 = __builtin_amdgcn_mfma_f32_16x16x32_bf16(kA[1][1], qb[js][1], s1, 0,0,0);

            unsigned int P0[2], P1[2];
            P0[0] = pk_fast(__expf(s0[0]), __expf(s0[1]));
            P0[1] = pk_fast(__expf(s0[2]), __expf(s0[3]));
            P1[0] = pk_fast(__expf(s1[0]), __expf(s1[1]));
            P1[1] = pk_fast(__expf(s1[2]), __expf(s1[3]));

            union { unsigned int u[4]; s16x8 v; } B;
            #pragma unroll
            for (int d = 0; d < 4; ++d) {
                int t0 = __builtin_amdgcn_ds_bpermute(addr[d], (int)P0[d & 1]);
                int t1 = __builtin_amdgcn_ds_bpermute(addr[d], (int)P1[d & 1]);
                B.u[d] = lowhalf ? (unsigned int)t0 : (unsigned int)t1;
            }
            #pragma unroll
            for (int cs = 0; cs < 4; ++cs)
                acc[js][cs] = __builtin_amdgcn_mfma_f32_16x16x32_bf16(
                    vA[cs], B.v, acc[js][cs], 0,0,0);
        }
        __syncthreads();
    }

    float* Up = U + ((size_t)iq * NB + b) * NPOS * CH;
    #pragma unroll
    for (int js = 0; js < 2; ++js)
        #pragma unroll
        for (int cs = 0; cs < 4; ++cs)
            *(f32x4*)&Up[(size_t)(j0 + w * 32 + js * 16 + lm) * CH
                         + cs * 16 + lq * 4] = acc[js][cs];
}

// ---------------------------------------------------------------------------
// Kernel 5: post projection + residual.  B = (U0+U1+U2+U3) bf16, A = Wpost
// bf16, epilogue adds x in fp32.  Block = (b, 32-pos).
// ---------------------------------------------------------------------------
__global__ __launch_bounds__(256) void post_kernel(
    const float* __restrict__ x, const float* __restrict__ Wpost,
    const float* __restrict__ U, float* __restrict__ out)
{
    const int b  = blockIdx.y;
    const int p0 = blockIdx.x * 32;
    const int tid = threadIdx.x;
    const int w = tid >> 6, l = tid & 63, lm = l & 15, lq = l >> 4;
    const int psub = (w & 1) * 16, ohalf = w >> 1;
    const int p = p0 + psub + lm;
    const size_t PS = (size_t)NB * NPOS * CH;

    const float* u = U + ((size_t)b * NPOS + p) * CH;
    s16x8 Bf[2];
    #pragma unroll
    for (int ck = 0; ck < 2; ++ck) {
        const float* ub = u + ck * 32 + lq * 8;
        float sv[8];
        #pragma unroll
        for (int j = 0; j < 8; ++j)
            sv[j] = ub[j] + ub[PS + j] + ub[2 * PS + j] + ub[3 * PS + j];
        union { unsigned int u[4]; s16x8 v; } cb;
        #pragma unroll
        for (int j = 0; j < 4; ++j) cb.u[j] = pk_rne(sv[2*j], sv[2*j+1]);
        Bf[ck] = cb.v;
    }

    #pragma unroll
    for (int ot = 0; ot < 4; ++ot) {
        const int o0 = (ohalf * 4 + ot) * 16;
        f32x4 acc = {0.f, 0.f, 0.f, 0.f};
        #pragma unroll
        for (int ck = 0; ck < 2; ++ck) {
            const float* wp = Wpost + (o0 + lm) * CH + ck * 32 + lq * 8;
            union { unsigned int u[4]; s16x8 v; } ca;
            #pragma unroll
            for (int j = 0; j < 4; ++j) ca.u[j] = pk_rne(wp[2*j], wp[2*j+1]);
            acc = __builtin_amdgcn_mfma_f32_16x16x32_bf16(ca.v, Bf[ck], acc, 0,0,0);
        }
        #pragma unroll
        for (int r = 0; r < 4; ++r) {
            size_t gi = ((size_t)b * CIN + o0 + lq * 4 + r) * NPOS + p;
            out[gi] = x[gi] + acc[r];
        }
    }
}

extern "C" void kernel_launch(void* const* d_in, const int* in_sizes, int n_in,
                              void* d_out, int out_size, void* d_ws, size_t ws_size,
                              hipStream_t stream) {
    const float* x     = (const float*)d_in[0];
    const float* Wq    = (const float*)d_in[1];
    const float* Wk    = (const float*)d_in[2];
    const float* Wv    = (const float*)d_in[3];
    const float* Wpost = (const float*)d_in[4];
    float* out = (float*)d_out;

    // ws: kT(1MB) qT(1MB) vbs(1MB) lpart(128KB) U(8MB, 4 fp32 partials;
    // first 2MB doubles as v32, consumed by combine before agg writes U)
    unsigned short* kT  = (unsigned short*)d_ws;
    unsigned short* qT  = kT + (size_t)NB * NPOS * CH;
    unsigned short* vbs = qT + (size_t)NB * NPOS * CH;
    float* lpart = (float*)(vbs + (size_t)NB * NPOS * CH);
    float* U     = lpart + (size_t)4 * NB * NPOS;
    float* v32   = U;   // overlay

    qkv_kernel    <<<dim3(NPOS / 32, NB),   256, 0, stream>>>(x, Wq, Wk, Wv, kT, qT, v32);
    stats_kernel  <<<dim3(NPOS / 128, 4, NB), 256, 0, stream>>>(kT, qT, lpart);
    combine_kernel<<<dim3(NB * CH * NPOS / 1024), 256, 0, stream>>>(lpart, v32, vbs);
    agg_kernel    <<<dim3(NPOS / 128, 4, NB), 256, 0, stream>>>(kT, qT, vbs, U);
    post_kernel   <<<dim3(NPOS / 32, NB),   256, 0, stream>>>(x, Wpost, U, out);
}

// Round 5
// 109.864 us; speedup vs baseline: 4.1629x; 1.1474x over previous
//
#include <hip/hip_runtime.h>
#include <math.h>

#define NB   2
#define CIN  128
#define CH   64
#define NPOS 4096

typedef __attribute__((ext_vector_type(8))) short s16x8;   // 8 bf16 (4 VGPRs)
typedef __attribute__((ext_vector_type(4))) float f32x4;

__device__ __forceinline__ unsigned int bfrne(float f) {
    unsigned int u = __float_as_uint(f);
    return (u + 0x7FFFu + ((u >> 16) & 1u)) >> 16;
}
__device__ __forceinline__ unsigned int pk_rne(float lo, float hi) {
    return bfrne(lo) | (bfrne(hi) << 16);
}
// fast half-up pack for non-negative values (exp outputs)
__device__ __forceinline__ unsigned int pk_fast(float lo, float hi) {
    unsigned int a = (__float_as_uint(lo) + 0x8000u) >> 16;
    unsigned int b = (__float_as_uint(hi) + 0x8000u) & 0xFFFF0000u;
    return a | b;
}
__device__ __forceinline__ float bf2f(unsigned short h) {
    return __uint_as_float(((unsigned int)h) << 16);
}

// ---------------------------------------------------------------------------
// Kernel 0: pack all weights to bf16 once.  Wb: [Wq|Wk|Wv|Wpost], 8192 each.
// ---------------------------------------------------------------------------
__global__ __launch_bounds__(256) void packw_kernel(
    const float* __restrict__ Wq, const float* __restrict__ Wk,
    const float* __restrict__ Wv, const float* __restrict__ Wpost,
    unsigned short* __restrict__ Wb)
{
    const int gid = blockIdx.x * 256 + threadIdx.x;   // 8192 threads
    const int base = gid * 4;
    const int mat = base >> 13, off = base & 8191;
    const float* src = (mat == 0) ? Wq : (mat == 1) ? Wk : (mat == 2) ? Wv : Wpost;
    float4 f = *(const float4*)&src[off];
    uint2 st = make_uint2(pk_rne(f.x, f.y), pk_rne(f.z, f.w));
    *(uint2*)&Wb[mat * 8192 + off] = st;
}

// ---------------------------------------------------------------------------
// Kernel 1: q/k/v projections via MFMA.  16-pos tiles -> 512 blocks (2/CU).
// x staged+transposed in LDS; B = x split hi+lo bf16 (fp32-x accuracy);
// A = pre-packed bf16 W (direct s16x8 loads).  Each wave: 3 of 12 o-tiles.
//   kT,qT: (b,pos,c) bf16;  v32: (b,c,pos) fp32.
// ---------------------------------------------------------------------------
#define XTS 132
__global__ __launch_bounds__(256) void qkv_kernel(
    const float* __restrict__ x, const unsigned short* __restrict__ Wb,
    unsigned short* __restrict__ kT, unsigned short* __restrict__ qT,
    float* __restrict__ v32)
{
    __shared__ __align__(16) float xT[16 * XTS];   // 8.25 KB
    const int b  = blockIdx.y;
    const int p0 = blockIdx.x * 16;
    const int tid = threadIdx.x;

    #pragma unroll
    for (int it = 0; it < 2; ++it) {
        int idx = it * 256 + tid;                  // 0..511
        int c = idx >> 2, p4 = (idx & 3) * 4;
        float4 g = *(const float4*)&x[((size_t)b * CIN + c) * NPOS + p0 + p4];
        xT[(p4 + 0) * XTS + c] = g.x;
        xT[(p4 + 1) * XTS + c] = g.y;
        xT[(p4 + 2) * XTS + c] = g.z;
        xT[(p4 + 3) * XTS + c] = g.w;
    }
    __syncthreads();

    const int w = tid >> 6, l = tid & 63, lm = l & 15, lq = l >> 4;
    const int p = p0 + lm;

    s16x8 Bhi[4], Blo[4];
    #pragma unroll
    for (int ck = 0; ck < 4; ++ck) {
        const float* xr = &xT[lm * XTS + ck * 32 + lq * 8];
        union { unsigned int u[4]; s16x8 v; } chv, clv;
        #pragma unroll
        for (int j = 0; j < 4; ++j) {
            float x0 = xr[2 * j], x1 = xr[2 * j + 1];
            unsigned int h0 = bfrne(x0), h1 = bfrne(x1);
            chv.u[j] = h0 | (h1 << 16);
            clv.u[j] = pk_rne(x0 - __uint_as_float(h0 << 16),
                              x1 - __uint_as_float(h1 << 16));
        }
        Bhi[ck] = chv.v; Blo[ck] = clv.v;
    }

    #pragma unroll
    for (int t3 = 0; t3 < 3; ++t3) {
        const int tile = w * 3 + t3;
        const int mat = tile >> 2, o0 = (tile & 3) * 16;
        const unsigned short* Wm = Wb + mat * 8192;
        f32x4 acc = {0.f, 0.f, 0.f, 0.f};
        #pragma unroll
        for (int ck = 0; ck < 4; ++ck) {
            s16x8 aW = *(const s16x8*)&Wm[(o0 + lm) * CIN + ck * 32 + lq * 8];
            acc = __builtin_amdgcn_mfma_f32_16x16x32_bf16(aW, Bhi[ck], acc, 0,0,0);
            acc = __builtin_amdgcn_mfma_f32_16x16x32_bf16(aW, Blo[ck], acc, 0,0,0);
        }
        if (mat < 2) {
            unsigned short* dst = (mat == 0) ? qT : kT;
            uint2 st = make_uint2(pk_rne(acc[0], acc[1]), pk_rne(acc[2], acc[3]));
            *(uint2*)&dst[((size_t)b * NPOS + p) * CH + o0 + lq * 4] = st;
        } else {
            #pragma unroll
            for (int r = 0; r < 4; ++r)
                v32[((size_t)b * CH + o0 + lq * 4 + r) * NPOS + p] = acc[r];
        }
    }
}

// ---------------------------------------------------------------------------
// Kernel 2: softmax denominator partials over j-EIGHTHS (512 blocks, 2/CU).
// lpart[jq][b][i] = sum over jq-th 512-j slice of exp(s[i,j]).
// Block = (128-i, jq, b); wave w owns 32 i (A-frags reg-resident); q staged
// per 64-j tile in frag-ordered LDS (lane l at l*16B, conflict-free).
// ---------------------------------------------------------------------------
__global__ __launch_bounds__(256) void stats_kernel(
    const unsigned short* __restrict__ kT,
    const unsigned short* __restrict__ qT,
    float* __restrict__ lpart)
{
    __shared__ __align__(16) unsigned short qbuf[4096];   // 8 KB
    const int b  = blockIdx.z;
    const int jq = blockIdx.y;
    const int i0 = blockIdx.x * 128;
    const int tid = threadIdx.x;
    const int w = tid >> 6, l = tid & 63, lm = l & 15, lq = l >> 4;

    s16x8 a[2][2];
    #pragma unroll
    for (int s = 0; s < 2; ++s)
        #pragma unroll
        for (int kc = 0; kc < 2; ++kc)
            a[s][kc] = *(const s16x8*)&kT[
                ((size_t)b * NPOS + i0 + w * 32 + s * 16 + lm) * CH + kc * 32 + lq * 8];

    const unsigned short* qpt =
        qT + ((size_t)b * NPOS + jq * 512 + w * 16 + lm) * CH + lq * 8;
    s16x8 st0 = *(const s16x8*)(qpt);
    s16x8 st1 = *(const s16x8*)(qpt + 32);

    float rs[2][4] = {};
    for (int t = 0; t < 8; ++t) {
        *(s16x8*)&qbuf[(2 * w + 0) * 512 + l * 8] = st0;
        *(s16x8*)&qbuf[(2 * w + 1) * 512 + l * 8] = st1;
        __syncthreads();
        if (t < 7) {
            const unsigned short* qn = qpt + (size_t)(t + 1) * 64 * CH;
            st0 = *(const s16x8*)(qn);
            st1 = *(const s16x8*)(qn + 32);
        }
        #pragma unroll
        for (int js = 0; js < 4; ++js) {
            s16x8 b0 = *(const s16x8*)&qbuf[(js * 2 + 0) * 512 + l * 8];
            s16x8 b1 = *(const s16x8*)&qbuf[(js * 2 + 1) * 512 + l * 8];
            #pragma unroll
            for (int s = 0; s < 2; ++s) {
                f32x4 sc = {0.f, 0.f, 0.f, 0.f};
                sc = __builtin_amdgcn_mfma_f32_16x16x32_bf16(a[s][0], b0, sc, 0,0,0);
                sc = __builtin_amdgcn_mfma_f32_16x16x32_bf16(a[s][1], b1, sc, 0,0,0);
                rs[s][0] += __expf(sc[0]); rs[s][1] += __expf(sc[1]);
                rs[s][2] += __expf(sc[2]); rs[s][3] += __expf(sc[3]);
            }
        }
        __syncthreads();
    }

    #pragma unroll
    for (int s = 0; s < 2; ++s)
        #pragma unroll
        for (int r = 0; r < 4; ++r) {
            #pragma unroll
            for (int m = 1; m < 16; m <<= 1)
                rs[s][r] += __shfl_xor(rs[s][r], m);
        }
    if (lm == 0) {
        #pragma unroll
        for (int s = 0; s < 2; ++s)
            #pragma unroll
            for (int r = 0; r < 4; ++r)
                lpart[(size_t)jq * NB * NPOS + b * NPOS
                      + i0 + w * 32 + s * 16 + lq * 4 + r] = rs[s][r];
    }
}

// ---------------------------------------------------------------------------
// Kernel 3: combine 8 partial denominators and prescale v:
//   vbs[c,i] = bf16( v32[c,i] / (sum_q lpart[q][i]) )
// ---------------------------------------------------------------------------
__global__ __launch_bounds__(256) void combine_kernel(
    const float* __restrict__ lpart, const float* __restrict__ v32,
    unsigned short* __restrict__ vbs)
{
    const int idx4 = blockIdx.x * 256 + threadIdx.x;
    const int base = idx4 * 4;                 // flat (b,c,i)
    const int b = base >> 18;
    const int i = base & (NPOS - 1);
    const float* lp = lpart + b * NPOS + i;
    float sx = 0.f, sy = 0.f, sz = 0.f, sw = 0.f;
    #pragma unroll
    for (int qq = 0; qq < 8; ++qq) {
        float4 lv = *(const float4*)(lp + (size_t)qq * NB * NPOS);
        sx += lv.x; sy += lv.y; sz += lv.z; sw += lv.w;
    }
    float4 v = *(const float4*)&v32[base];
    uint2 st = make_uint2(pk_rne(v.x / sx, v.y / sy),
                          pk_rne(v.z / sz, v.w / sw));
    *(uint2*)&vbs[base] = st;
}

// ---------------------------------------------------------------------------
// Kernel 4: aggregation over i-EIGHTHS (512 blocks, 2/CU).  U[iq][b][j][c]
// bf16 partials.  Block = (128-j, iq, b), 4 waves; wave owns 32 j (q-frags
// reg-resident, 64c x 32j accumulator).  Per 32-i iter: k/v tiles staged in
// frag-ordered LDS (reg-prefetched); 8 score MFMAs -> exp -> bpermute C->B
// transpose -> 8 PV MFMAs.  16 iters, 2 barriers each.
// ---------------------------------------------------------------------------
__global__ __launch_bounds__(256) void agg_kernel(
    const unsigned short* __restrict__ kT,
    const unsigned short* __restrict__ qT,
    const unsigned short* __restrict__ vbs,
    unsigned short* __restrict__ U)
{
    __shared__ __align__(16) unsigned short kbuf[2048];   // 4 KB
    __shared__ __align__(16) unsigned short vbuf[2048];   // 4 KB
    const int b  = blockIdx.z;
    const int iq = blockIdx.y;
    const int j0 = blockIdx.x * 128;
    const int tid = threadIdx.x;
    const int w = tid >> 6, l = tid & 63, lm = l & 15, lq = l >> 4;

    s16x8 qb[2][2];
    #pragma unroll
    for (int js = 0; js < 2; ++js)
        #pragma unroll
        for (int kc = 0; kc < 2; ++kc)
            qb[js][kc] = *(const s16x8*)&qT[
                ((size_t)b * NPOS + j0 + w * 32 + js * 16 + lm) * CH + kc * 32 + lq * 8];

    int addr[4];
    #pragma unroll
    for (int d = 0; d < 4; ++d)
        addr[d] = (lm + 16 * (2 * (lq & 1) + (d >> 1))) << 2;
    const bool lowhalf = (lq < 2);

    const unsigned short* kpt = kT
        + ((size_t)b * NPOS + iq * 512 + (w >> 1) * 16 + lm) * CH
        + (w & 1) * 32 + lq * 8;
    const unsigned short* vpt = vbs
        + ((size_t)b * CH + w * 16 + lm) * NPOS + iq * 512 + lq * 8;

    f32x4 acc[2][4] = {};
    s16x8 kst = *(const s16x8*)kpt;
    s16x8 vst = *(const s16x8*)vpt;

    for (int t = 0; t < 16; ++t) {
        *(s16x8*)&kbuf[w * 512 + l * 8] = kst;
        *(s16x8*)&vbuf[w * 512 + l * 8] = vst;
        __syncthreads();
        if (t < 15) {
            kst = *(const s16x8*)(kpt + (t + 1) * 32 * CH);
            vst = *(const s16x8*)(vpt + (t + 1) * 32);
        }
        s16x8 kA[2][2], vA[4];
        #pragma unroll
        for (int s = 0; s < 2; ++s)
            #pragma unroll
            for (int kc = 0; kc < 2; ++kc)
                kA[s][kc] = *(const s16x8*)&kbuf[(s * 2 + kc) * 512 + l * 8];
        #pragma unroll
        for (int cs = 0; cs < 4; ++cs)
            vA[cs] = *(const s16x8*)&vbuf[cs * 512 + l * 8];

        #pragma unroll
        for (int js = 0; js < 2; ++js) {
            f32x4 s0 = {0,0,0,0}, s1 = {0,0,0,0};
            s0 = __builtin_amdgcn_mfma_f32_16x16x32_bf16(kA[0][0], qb[js][0], s0, 0,0,0);
            s0 = __builtin_amdgcn_mfma_f32_16x16x32_bf16(kA[0][1], qb[js][1], s0, 0,0,0);
            s1 = __builtin_amdgcn_mfma_f32_16x16x32_bf16(kA[1][0], qb[js][0], s1, 0,0,0);
            s1 = __builtin_amdgcn_mfma_f32_16x16x32_bf16(kA[1][1], qb[js][1], s1, 0,0,0);

            unsigned int P0[2], P1[2];
            P0[0] = pk_fast(__expf(s0[0]), __expf(s0[1]));
            P0[1] = pk_fast(__expf(s0[2]), __expf(s0[3]));
            P1[0] = pk_fast(__expf(s1[0]), __expf(s1[1]));
            P1[1] = pk_fast(__expf(s1[2]), __expf(s1[3]));

            union { unsigned int u[4]; s16x8 v; } B;
            #pragma unroll
            for (int d = 0; d < 4; ++d) {
                int t0 = __builtin_amdgcn_ds_bpermute(addr[d], (int)P0[d & 1]);
                int t1 = __builtin_amdgcn_ds_bpermute(addr[d], (int)P1[d & 1]);
                B.u[d] = lowhalf ? (unsigned int)t0 : (unsigned int)t1;
            }
            #pragma unroll
            for (int cs = 0; cs < 4; ++cs)
                acc[js][cs] = __builtin_amdgcn_mfma_f32_16x16x32_bf16(
                    vA[cs], B.v, acc[js][cs], 0,0,0);
        }
        __syncthreads();
    }

    unsigned short* Up = U + ((size_t)iq * NB + b) * NPOS * CH;
    #pragma unroll
    for (int js = 0; js < 2; ++js)
        #pragma unroll
        for (int cs = 0; cs < 4; ++cs) {
            uint2 st = make_uint2(pk_rne(acc[js][cs][0], acc[js][cs][1]),
                                  pk_rne(acc[js][cs][2], acc[js][cs][3]));
            *(uint2*)&Up[(size_t)(j0 + w * 32 + js * 16 + lm) * CH
                         + cs * 16 + lq * 4] = st;
        }
}

// ---------------------------------------------------------------------------
// Kernel 5: post projection + residual.  B = sum of 8 bf16 U partials
// (fp32 accumulate), A = pre-packed Wpost bf16, epilogue adds x in fp32.
// Block = (b, 32-pos); 256 blocks.
// ---------------------------------------------------------------------------
__global__ __launch_bounds__(256) void post_kernel(
    const float* __restrict__ x, const unsigned short* __restrict__ Wb,
    const unsigned short* __restrict__ U, float* __restrict__ out)
{
    const int b  = blockIdx.y;
    const int p0 = blockIdx.x * 32;
    const int tid = threadIdx.x;
    const int w = tid >> 6, l = tid & 63, lm = l & 15, lq = l >> 4;
    const int psub = (w & 1) * 16, ohalf = w >> 1;
    const int p = p0 + psub + lm;
    const size_t PS = (size_t)NB * NPOS * CH;

    const unsigned short* u = U + ((size_t)b * NPOS + p) * CH;
    const unsigned short* Wpb = Wb + 3 * 8192;
    s16x8 Bf[2];
    #pragma unroll
    for (int ck = 0; ck < 2; ++ck) {
        float sv[8] = {};
        #pragma unroll
        for (int qq = 0; qq < 8; ++qq) {
            union { s16x8 v; unsigned short us[8]; } uu;
            uu.v = *(const s16x8*)(u + (size_t)qq * PS + ck * 32 + lq * 8);
            #pragma unroll
            for (int j = 0; j < 8; ++j) sv[j] += bf2f(uu.us[j]);
        }
        union { unsigned int u[4]; s16x8 v; } cb;
        #pragma unroll
        for (int j = 0; j < 4; ++j) cb.u[j] = pk_rne(sv[2*j], sv[2*j+1]);
        Bf[ck] = cb.v;
    }

    #pragma unroll
    for (int ot = 0; ot < 4; ++ot) {
        const int o0 = (ohalf * 4 + ot) * 16;
        f32x4 acc = {0.f, 0.f, 0.f, 0.f};
        #pragma unroll
        for (int ck = 0; ck < 2; ++ck) {
            s16x8 aW = *(const s16x8*)&Wpb[(o0 + lm) * CH + ck * 32 + lq * 8];
            acc = __builtin_amdgcn_mfma_f32_16x16x32_bf16(aW, Bf[ck], acc, 0,0,0);
        }
        #pragma unroll
        for (int r = 0; r < 4; ++r) {
            size_t gi = ((size_t)b * CIN + o0 + lq * 4 + r) * NPOS + p;
            out[gi] = x[gi] + acc[r];
        }
    }
}

extern "C" void kernel_launch(void* const* d_in, const int* in_sizes, int n_in,
                              void* d_out, int out_size, void* d_ws, size_t ws_size,
                              hipStream_t stream) {
    const float* x     = (const float*)d_in[0];
    const float* Wq    = (const float*)d_in[1];
    const float* Wk    = (const float*)d_in[2];
    const float* Wv    = (const float*)d_in[3];
    const float* Wpost = (const float*)d_in[4];
    float* out = (float*)d_out;

    // ws: kT(1MB) qT(1MB) vbs(1MB) Wb(64KB) lpart(256KB) U(8MB bf16, 8
    // partials; start of U doubles as v32 fp32, consumed before agg writes)
    unsigned short* kT  = (unsigned short*)d_ws;
    unsigned short* qT  = kT + (size_t)NB * NPOS * CH;
    unsigned short* vbs = qT + (size_t)NB * NPOS * CH;
    unsigned short* Wb  = vbs + (size_t)NB * NPOS * CH;
    float* lpart = (float*)(Wb + 4 * 8192);
    unsigned short* U = (unsigned short*)(lpart + (size_t)8 * NB * NPOS);
    float* v32 = (float*)U;   // overlay

    packw_kernel  <<<dim3(32), 256, 0, stream>>>(Wq, Wk, Wv, Wpost, Wb);
    qkv_kernel    <<<dim3(NPOS / 16, NB), 256, 0, stream>>>(x, Wb, kT, qT, v32);
    stats_kernel  <<<dim3(NPOS / 128, 8, NB), 256, 0, stream>>>(kT, qT, lpart);
    combine_kernel<<<dim3(NB * CH * NPOS / 1024), 256, 0, stream>>>(lpart, v32, vbs);
    agg_kernel    <<<dim3(NPOS / 128, 8, NB), 256, 0, stream>>>(kT, qT, vbs, U);
    post_kernel   <<<dim3(NPOS / 32, NB), 256, 0, stream>>>(x, Wb, U, out);
}